// Round 3
// baseline (1437.588 us; speedup 1.0000x reference)
//
#include <hip/hip_runtime.h>
#include <math.h>

#define B_ 4
#define T_ 2048
#define C_ 1024
#define D_ 64
#define N_ 16384
#define K_ 32
#define SCALE 0.03125f   // 1/sqrt(1024)
#define NEGINF -3.402823e38f
#define CQ 4             // queries per causal block

// ---------------------------------------------------------------------------
// QKV projection (unchanged)
// ---------------------------------------------------------------------------
__global__ __launch_bounds__(192) void qkv_proj_kernel(
    const float* __restrict__ x,
    const float* __restrict__ Wq, const float* __restrict__ bq,
    const float* __restrict__ Wk, const float* __restrict__ bk,
    const float* __restrict__ Wv, const float* __restrict__ bvp,
    float* __restrict__ q, float* __restrict__ k, float* __restrict__ v)
{
    __shared__ float xs[8][C_];
    const int tid = threadIdx.x;
    const int row0 = blockIdx.x * 8;
    const float* xr = x + (size_t)row0 * C_;
    for (int i = tid; i < 8 * C_ / 4; i += 192)
        ((float4*)&xs[0][0])[i] = ((const float4*)xr)[i];
    __syncthreads();
    const int g = tid >> 6;
    const int d = tid & 63;
    const float* W    = (g == 0) ? Wq : (g == 1) ? Wk : Wv;
    const float* bias = (g == 0) ? bq : (g == 1) ? bk : bvp;
    float*       o    = (g == 0) ? q  : (g == 1) ? k  : v;
    float acc[8];
    const float b0 = bias[d];
    #pragma unroll
    for (int r = 0; r < 8; ++r) acc[r] = b0;
    #pragma unroll 4
    for (int c = 0; c < C_; ++c) {
        const float wv = W[c * D_ + d];
        #pragma unroll
        for (int r = 0; r < 8; ++r) acc[r] += xs[r][c] * wv;
    }
    #pragma unroll
    for (int r = 0; r < 8; ++r)
        o[(size_t)(row0 + r) * D_ + d] = acc[r];
}

// ---------------------------------------------------------------------------
// Transpose mem_keys [B][N][D] -> kT [B][D][N]  (unchanged)
// ---------------------------------------------------------------------------
__global__ __launch_bounds__(256) void transpose_keys_kernel(
    const float* __restrict__ keys, float* __restrict__ kT)
{
    __shared__ float tile[64][68];
    const int tid = threadIdx.x;
    const int b  = blockIdx.x >> 8;
    const int n0 = (blockIdx.x & 255) << 6;
    const float4* in4 = (const float4*)(keys + ((size_t)b * N_ + n0) * D_);
    #pragma unroll
    for (int p = 0; p < 4; ++p) {
        const int fi = tid + p * 256;
        const int n = fi >> 4, c4 = fi & 15;
        const float4 v = in4[n * 16 + c4];
        *(float4*)&tile[n][c4 * 4] = v;
    }
    __syncthreads();
    #pragma unroll
    for (int p = 0; p < 4; ++p) {
        const int fi = tid + p * 256;
        const int d = fi >> 4, n4 = fi & 15;
        float4 v;
        v.x = tile[n4 * 4 + 0][d];
        v.y = tile[n4 * 4 + 1][d];
        v.z = tile[n4 * 4 + 2][d];
        v.w = tile[n4 * 4 + 3][d];
        *(float4*)(kT + ((size_t)b * D_ + d) * N_ + n0 + n4 * 4) = v;
    }
}

// ---------------------------------------------------------------------------
// Causal attention, CQ=4 queries per block: K/V row loads amortized 4x.
// Invalid (future) scores written as NEGINF -> all later passes branch-free.
// ---------------------------------------------------------------------------
__global__ __launch_bounds__(256) void causal_attn_kernel(
    const float* __restrict__ q, const float* __restrict__ k,
    const float* __restrict__ v, float* __restrict__ outc)
{
    __shared__ float qs[CQ][D_];
    __shared__ float sc[CQ][T_];
    __shared__ float red[4][CQ][D_];
    __shared__ float redw[CQ][4];
    const int tid = threadIdx.x;
    const int bid = blockIdx.x;                     // 2048 blocks
    const int b  = (bid & 7) >> 1;                  // batch pinned to XCD pair
    const int tg = ((bid >> 3) << 1) | (bid & 1);   // 0..511
    const int t0 = tg * CQ;
    if (tid < CQ * 64)
        qs[tid >> 6][tid & 63] =
            q[((size_t)b * T_ + t0 + (tid >> 6)) * D_ + (tid & 63)];
    __syncthreads();
    const int nS = t0 + CQ;                         // keys 0..t0+CQ-1
    const float* kb = k + (size_t)b * T_ * D_;
    for (int s = tid; s < nS; s += 256) {
        const float* kr = kb + (size_t)s * D_;
        float dot[CQ] = {0.f, 0.f, 0.f, 0.f};
        #pragma unroll
        for (int d = 0; d < D_; d += 4) {
            const float4 k4 = *(const float4*)(kr + d);
            #pragma unroll
            for (int qq = 0; qq < CQ; ++qq) {
                dot[qq] += qs[qq][d]     * k4.x + qs[qq][d + 1] * k4.y
                         + qs[qq][d + 2] * k4.z + qs[qq][d + 3] * k4.w;
            }
        }
        #pragma unroll
        for (int qq = 0; qq < CQ; ++qq)
            sc[qq][s] = (s <= t0 + qq) ? dot[qq] * SCALE : NEGINF;
    }
    __syncthreads();
    // row max
    float lm[CQ] = {NEGINF, NEGINF, NEGINF, NEGINF};
    for (int s = tid; s < nS; s += 256) {
        #pragma unroll
        for (int qq = 0; qq < CQ; ++qq) lm[qq] = fmaxf(lm[qq], sc[qq][s]);
    }
    #pragma unroll
    for (int qq = 0; qq < CQ; ++qq) {
        float x2 = lm[qq];
        #pragma unroll
        for (int off = 32; off; off >>= 1) x2 = fmaxf(x2, __shfl_xor(x2, off));
        if ((tid & 63) == 0) redw[qq][tid >> 6] = x2;
    }
    __syncthreads();
    float m[CQ];
    #pragma unroll
    for (int qq = 0; qq < CQ; ++qq)
        m[qq] = fmaxf(fmaxf(redw[qq][0], redw[qq][1]),
                      fmaxf(redw[qq][2], redw[qq][3]));
    __syncthreads();
    // exp + sum
    float ls[CQ] = {0.f, 0.f, 0.f, 0.f};
    for (int s = tid; s < nS; s += 256) {
        #pragma unroll
        for (int qq = 0; qq < CQ; ++qq) {
            const float w2 = (s <= t0 + qq) ? __expf(sc[qq][s] - m[qq]) : 0.f;
            sc[qq][s] = w2;
            ls[qq] += w2;
        }
    }
    #pragma unroll
    for (int qq = 0; qq < CQ; ++qq) {
        float x2 = ls[qq];
        #pragma unroll
        for (int off = 32; off; off >>= 1) x2 += __shfl_xor(x2, off);
        if ((tid & 63) == 0) redw[qq][tid >> 6] = x2;
    }
    __syncthreads();
    float l[CQ];
    #pragma unroll
    for (int qq = 0; qq < CQ; ++qq)
        l[qq] = redw[qq][0] + redw[qq][1] + redw[qq][2] + redw[qq][3];
    // PV: v row loaded once, used for 4 queries
    const int g = tid >> 6, d = tid & 63;
    const float* vb = v + (size_t)b * T_ * D_;
    float acc[CQ] = {0.f, 0.f, 0.f, 0.f};
    for (int s = g; s < nS; s += 4) {
        const float vv = vb[(size_t)s * D_ + d];
        #pragma unroll
        for (int qq = 0; qq < CQ; ++qq) acc[qq] += sc[qq][s] * vv;
    }
    #pragma unroll
    for (int qq = 0; qq < CQ; ++qq) red[g][qq][d] = acc[qq];
    __syncthreads();
    if (g == 0) {
        #pragma unroll
        for (int qq = 0; qq < CQ; ++qq)
            outc[((size_t)b * T_ + t0 + qq) * D_ + d] =
                (red[0][qq][d] + red[1][qq][d] + red[2][qq][d] + red[3][qq][d]) / l[qq];
    }
}

// ---------------------------------------------------------------------------
// kNN top-k v3: key-split KS=2.  Grid 2048 blocks (8 blocks/CU -> 32 waves/CU).
// Block (b, s, qt): 8 queries x 8192 keys; per-wave 2 queries, scores in regs,
// running sorted top-32 in lanes 0..31 with early-stopped extraction.
// Writes (val, idx) candidates to scratch; merge kernel finishes.
// Swizzle: each XCD gets one (batch, key-half) 2 MB panel.
// ---------------------------------------------------------------------------
__global__ __launch_bounds__(256) void knn_topk_kernel(
    const float* __restrict__ qg, const float* __restrict__ kT,
    float* __restrict__ cval, int* __restrict__ cidx)
{
    __shared__ float q_lds[4][2][64];
    const int tid = threadIdx.x;
    const int w = tid >> 6, lane = tid & 63;
    const int bid = blockIdx.x;
    const int b  = (bid & 7) >> 1;      // batch
    const int s  = bid & 1;             // key half
    const int qt = bid >> 3;            // 0..255
    const int t0 = qt * 8 + w * 2;

    #pragma unroll
    for (int qq = 0; qq < 2; ++qq)
        q_lds[w][qq][lane] = qg[((size_t)(b * T_ + t0 + qq)) * D_ + lane];
    __syncthreads();

    const float4* kT4 = (const float4*)(kT + (size_t)b * D_ * N_);

    float rv[2];  int rid[2];
    rv[0] = rv[1] = NEGINF;
    rid[0] = rid[1] = 0x7fffffff;

    for (int c = 0; c < 8; ++c) {
        // scores for chunk c: lane covers keys s*8192 + c*1024 + g*256 + lane*4 + j
        float sreg[2][16];
        #pragma unroll
        for (int qq = 0; qq < 2; ++qq)
            #pragma unroll
            for (int j = 0; j < 16; ++j) sreg[qq][j] = 0.f;

        for (int dt = 0; dt < 8; ++dt) {
            float qv[2][8];
            #pragma unroll
            for (int qq = 0; qq < 2; ++qq)
                #pragma unroll
                for (int dd = 0; dd < 8; ++dd)
                    qv[qq][dd] = q_lds[w][qq][dt * 8 + dd];
            #pragma unroll
            for (int g = 0; g < 4; ++g) {
                #pragma unroll
                for (int dd = 0; dd < 8; ++dd) {
                    const float4 kf =
                        kT4[(size_t)(dt * 8 + dd) * (N_ / 4) + s * 2048 + c * 256 + g * 64 + lane];
                    #pragma unroll
                    for (int qq = 0; qq < 2; ++qq) {
                        sreg[qq][g * 4 + 0] += kf.x * qv[qq][dd];
                        sreg[qq][g * 4 + 1] += kf.y * qv[qq][dd];
                        sreg[qq][g * 4 + 2] += kf.z * qv[qq][dd];
                        sreg[qq][g * 4 + 3] += kf.w * qv[qq][dd];
                    }
                }
            }
        }

        // early-stopped extraction into running top-32
        #pragma unroll
        for (int qq = 0; qq < 2; ++qq) {
            float lmax = NEGINF; int lslot = 0;
            #pragma unroll
            for (int j = 0; j < 16; ++j)
                if (sreg[qq][j] > lmax) { lmax = sreg[qq][j]; lslot = j; }
            float t32 = __shfl(rv[qq], 31);
            for (int it = 0; it < 32; ++it) {
                float wm = lmax;
                #pragma unroll
                for (int off = 32; off; off >>= 1)
                    wm = fmaxf(wm, __shfl_xor(wm, off));
                if (wm <= t32) break;
                const unsigned long long bal = __ballot(lmax == wm);
                const int winner = __ffsll((unsigned long long)bal) - 1;
                const int wslot  = __shfl(lslot, winner);
                const int widx   = (s << 13) + (c << 10) + ((wslot >> 2) << 8)
                                 + (winner << 2) + (wslot & 3);
                const unsigned long long gb = __ballot((lane < K_) && (rv[qq] > wm));
                const int pos = __popcll(gb);
                const float sv = __shfl_up(rv[qq], 1);
                const int   si = __shfl_up(rid[qq], 1);
                if (lane > pos)       { rv[qq] = sv; rid[qq] = si; }
                else if (lane == pos) { rv[qq] = wm; rid[qq] = widx; }
                t32 = __shfl(rv[qq], 31);
                if (lane == winner) {
                    float nm = NEGINF; int ns = 0;
                    #pragma unroll
                    for (int j = 0; j < 16; ++j) {
                        const float vj = (j == lslot) ? NEGINF : sreg[qq][j];
                        sreg[qq][j] = vj;
                        if (vj > nm) { nm = vj; ns = j; }
                    }
                    lmax = nm; lslot = ns;
                }
            }
        }
        __syncthreads();   // keep waves chunk-aligned for L2 reuse
    }

    // write candidates
    #pragma unroll
    for (int qq = 0; qq < 2; ++qq) {
        if (lane < K_) {
            const size_t qglob = (size_t)b * T_ + t0 + qq;
            cval[qglob * 64 + s * 32 + lane] = rv[qq];
            cidx[qglob * 64 + s * 32 + lane] = rid[qq];
        }
    }
}

// ---------------------------------------------------------------------------
// Merge 2x32 candidates -> top-32, softmax, V gather, gated combine.
// One wave per query (4 queries per block).
// ---------------------------------------------------------------------------
__global__ __launch_bounds__(256) void knn_merge_kernel(
    const float* __restrict__ cval, const int* __restrict__ cidx,
    const float* __restrict__ mem_vals, const float* __restrict__ outc,
    const float* __restrict__ gate, float* __restrict__ outp)
{
    __shared__ float wsel[4][K_];
    __shared__ int   isel[4][K_];
    const int tid = threadIdx.x;
    const int w = tid >> 6, lane = tid & 63;
    const int qglob = blockIdx.x * 4 + w;           // grid 2048 -> 8192 queries
    const int b = qglob >> 11;
    const float vv = cval[(size_t)qglob * 64 + lane];
    const int   ii = cidx[(size_t)qglob * 64 + lane];
    // rank among 64 (value desc, index asc tie-break)
    int rank = 0;
    for (int j = 0; j < 64; ++j) {
        const float ov = __shfl(vv, j);
        const int   oi = __shfl(ii, j);
        if (ov > vv || (ov == vv && oi < ii)) ++rank;
    }
    float m = vv;
    #pragma unroll
    for (int off = 32; off; off >>= 1) m = fmaxf(m, __shfl_xor(m, off));
    const float wgt = (rank < K_) ? __expf((vv - m) * SCALE) : 0.f;
    float ssum = wgt;
    #pragma unroll
    for (int off = 32; off; off >>= 1) ssum += __shfl_xor(ssum, off);
    if (rank < K_) { wsel[w][rank] = wgt; isel[w][rank] = ii; }
    __syncthreads();
    const float* vb = mem_vals + (size_t)b * N_ * D_;
    float acc = 0.f;
    #pragma unroll 4
    for (int j = 0; j < K_; ++j)
        acc += wsel[w][j] * vb[(size_t)isel[w][j] * D_ + lane];
    const float gv = gate[0];
    const size_t o = (size_t)qglob * D_ + lane;
    outp[o] = outc[o] * gv + (acc / ssum) * (1.f - gv);
}

extern "C" void kernel_launch(void* const* d_in, const int* in_sizes, int n_in,
                              void* d_out, int out_size, void* d_ws, size_t ws_size,
                              hipStream_t stream) {
    const float* x        = (const float*)d_in[0];
    const float* mem_keys = (const float*)d_in[1];
    const float* mem_vals = (const float*)d_in[2];
    const float* Wq       = (const float*)d_in[3];
    const float* bq       = (const float*)d_in[4];
    const float* Wk       = (const float*)d_in[5];
    const float* bk       = (const float*)d_in[6];
    const float* Wv       = (const float*)d_in[7];
    const float* bv       = (const float*)d_in[8];
    const float* gate     = (const float*)d_in[9];
    float* out = (float*)d_out;

    const size_t btd = (size_t)B_ * T_ * D_;   // 524288
    float* q    = (float*)d_ws;
    float* k    = q + btd;
    float* v    = k + btd;
    float* outc = v + btd;
    float* kT   = outc + btd;                  // [B][D][N] 16 MB
    float* cval = kT + (size_t)B_ * D_ * N_;   // [8192][64]
    int*   cidx = (int*)(cval + (size_t)B_ * T_ * 64);

    qkv_proj_kernel<<<B_ * T_ / 8, 192, 0, stream>>>(x, Wq, bq, Wk, bk, Wv, bv, q, k, v);
    transpose_keys_kernel<<<B_ * (N_ / 64), 256, 0, stream>>>(mem_keys, kT);
    causal_attn_kernel<<<(B_ * T_) / CQ, 256, 0, stream>>>(q, k, v, outc);
    knn_topk_kernel<<<(B_ * T_ / 8) * 2, 256, 0, stream>>>(q, kT, cval, cidx);
    knn_merge_kernel<<<(B_ * T_) / 4, 256, 0, stream>>>(cval, cidx, mem_vals, outc, gate, out);
}

// Round 4
// 1167.482 us; speedup vs baseline: 1.2314x; 1.2314x over previous
//
#include <hip/hip_runtime.h>
#include <math.h>

#define B_ 4
#define T_ 2048
#define C_ 1024
#define D_ 64
#define N_ 16384
#define K_ 32
#define SCALE 0.03125f   // 1/sqrt(1024)
#define NEGINF -3.402823e38f

// ---------------------------------------------------------------------------
// QKV projection (unchanged)
// ---------------------------------------------------------------------------
__global__ __launch_bounds__(192) void qkv_proj_kernel(
    const float* __restrict__ x,
    const float* __restrict__ Wq, const float* __restrict__ bq,
    const float* __restrict__ Wk, const float* __restrict__ bk,
    const float* __restrict__ Wv, const float* __restrict__ bvp,
    float* __restrict__ q, float* __restrict__ k, float* __restrict__ v)
{
    __shared__ float xs[8][C_];
    const int tid = threadIdx.x;
    const int row0 = blockIdx.x * 8;
    const float* xr = x + (size_t)row0 * C_;
    for (int i = tid; i < 8 * C_ / 4; i += 192)
        ((float4*)&xs[0][0])[i] = ((const float4*)xr)[i];
    __syncthreads();
    const int g = tid >> 6;
    const int d = tid & 63;
    const float* W    = (g == 0) ? Wq : (g == 1) ? Wk : Wv;
    const float* bias = (g == 0) ? bq : (g == 1) ? bk : bvp;
    float*       o    = (g == 0) ? q  : (g == 1) ? k  : v;
    float acc[8];
    const float b0 = bias[d];
    #pragma unroll
    for (int r = 0; r < 8; ++r) acc[r] = b0;
    #pragma unroll 4
    for (int c = 0; c < C_; ++c) {
        const float wv = W[c * D_ + d];
        #pragma unroll
        for (int r = 0; r < 8; ++r) acc[r] += xs[r][c] * wv;
    }
    #pragma unroll
    for (int r = 0; r < 8; ++r)
        o[(size_t)(row0 + r) * D_ + d] = acc[r];
}

// ---------------------------------------------------------------------------
// Transpose mem_keys [B][N][D] -> kT [B][D][N]  (unchanged)
// ---------------------------------------------------------------------------
__global__ __launch_bounds__(256) void transpose_keys_kernel(
    const float* __restrict__ keys, float* __restrict__ kT)
{
    __shared__ float tile[64][68];
    const int tid = threadIdx.x;
    const int b  = blockIdx.x >> 8;
    const int n0 = (blockIdx.x & 255) << 6;
    const float4* in4 = (const float4*)(keys + ((size_t)b * N_ + n0) * D_);
    #pragma unroll
    for (int p = 0; p < 4; ++p) {
        const int fi = tid + p * 256;
        const int n = fi >> 4, c4 = fi & 15;
        const float4 v = in4[n * 16 + c4];
        *(float4*)&tile[n][c4 * 4] = v;
    }
    __syncthreads();
    #pragma unroll
    for (int p = 0; p < 4; ++p) {
        const int fi = tid + p * 256;
        const int d = fi >> 4, n4 = fi & 15;
        float4 v;
        v.x = tile[n4 * 4 + 0][d];
        v.y = tile[n4 * 4 + 1][d];
        v.z = tile[n4 * 4 + 2][d];
        v.w = tile[n4 * 4 + 3][d];
        *(float4*)(kT + ((size_t)b * D_ + d) * N_ + n0 + n4 * 4) = v;
    }
}

// ---------------------------------------------------------------------------
// Causal attention — reverted to the round-1 per-(b,t) version (no spills).
// ---------------------------------------------------------------------------
__global__ __launch_bounds__(256) void causal_attn_kernel(
    const float* __restrict__ q, const float* __restrict__ k,
    const float* __restrict__ v, float* __restrict__ outc)
{
    __shared__ float qs[D_];
    __shared__ float sc[T_];
    __shared__ float red[4][D_];
    __shared__ float redw[4];
    const int tid = threadIdx.x;
    const int b = blockIdx.x >> 11;
    const int t = blockIdx.x & (T_ - 1);
    if (tid < 64) qs[tid] = q[((size_t)b * T_ + t) * D_ + tid];
    __syncthreads();
    const int nS = t + 1;
    const float* kb = k + (size_t)b * T_ * D_;
    for (int s = tid; s < nS; s += 256) {
        const float* kr = kb + (size_t)s * D_;
        float dot = 0.f;
        #pragma unroll
        for (int d = 0; d < D_; d += 4) {
            const float4 k4 = *(const float4*)(kr + d);
            dot += qs[d]*k4.x + qs[d+1]*k4.y + qs[d+2]*k4.z + qs[d+3]*k4.w;
        }
        sc[s] = dot * SCALE;
    }
    __syncthreads();
    float lm = -3.0e38f;
    for (int s = tid; s < nS; s += 256) lm = fmaxf(lm, sc[s]);
    #pragma unroll
    for (int off = 32; off; off >>= 1) lm = fmaxf(lm, __shfl_xor(lm, off));
    if ((tid & 63) == 0) redw[tid >> 6] = lm;
    __syncthreads();
    const float m = fmaxf(fmaxf(redw[0], redw[1]), fmaxf(redw[2], redw[3]));
    __syncthreads();
    float ls = 0.f;
    for (int s = tid; s < nS; s += 256) {
        const float w = __expf(sc[s] - m);
        sc[s] = w;
        ls += w;
    }
    #pragma unroll
    for (int off = 32; off; off >>= 1) ls += __shfl_xor(ls, off);
    if ((tid & 63) == 0) redw[tid >> 6] = ls;
    __syncthreads();
    const float l = redw[0] + redw[1] + redw[2] + redw[3];
    const int g = tid >> 6, d = tid & 63;
    const float* vb = v + (size_t)b * T_ * D_;
    float acc = 0.f;
    for (int s = g; s < nS; s += 4) acc += sc[s] * vb[(size_t)s * D_ + d];
    red[g][d] = acc;
    __syncthreads();
    if (g == 0)
        outc[((size_t)b * T_ + t) * D_ + d] =
            (red[0][d] + red[1][d] + red[2][d] + red[3][d]) / l;
}

// ---------------------------------------------------------------------------
// kNN top-k (key-split KS=2, unchanged from round 2)
// ---------------------------------------------------------------------------
__global__ __launch_bounds__(256) void knn_topk_kernel(
    const float* __restrict__ qg, const float* __restrict__ kT,
    float* __restrict__ cval, int* __restrict__ cidx)
{
    __shared__ float q_lds[4][2][64];
    const int tid = threadIdx.x;
    const int w = tid >> 6, lane = tid & 63;
    const int bid = blockIdx.x;
    const int b  = (bid & 7) >> 1;      // batch
    const int s  = bid & 1;             // key half
    const int qt = bid >> 3;            // 0..255
    const int t0 = qt * 8 + w * 2;

    #pragma unroll
    for (int qq = 0; qq < 2; ++qq)
        q_lds[w][qq][lane] = qg[((size_t)(b * T_ + t0 + qq)) * D_ + lane];
    __syncthreads();

    const float4* kT4 = (const float4*)(kT + (size_t)b * D_ * N_);

    float rv[2];  int rid[2];
    rv[0] = rv[1] = NEGINF;
    rid[0] = rid[1] = 0x7fffffff;

    for (int c = 0; c < 8; ++c) {
        float sreg[2][16];
        #pragma unroll
        for (int qq = 0; qq < 2; ++qq)
            #pragma unroll
            for (int j = 0; j < 16; ++j) sreg[qq][j] = 0.f;

        for (int dt = 0; dt < 8; ++dt) {
            float qv[2][8];
            #pragma unroll
            for (int qq = 0; qq < 2; ++qq)
                #pragma unroll
                for (int dd = 0; dd < 8; ++dd)
                    qv[qq][dd] = q_lds[w][qq][dt * 8 + dd];
            #pragma unroll
            for (int g = 0; g < 4; ++g) {
                #pragma unroll
                for (int dd = 0; dd < 8; ++dd) {
                    const float4 kf =
                        kT4[(size_t)(dt * 8 + dd) * (N_ / 4) + s * 2048 + c * 256 + g * 64 + lane];
                    #pragma unroll
                    for (int qq = 0; qq < 2; ++qq) {
                        sreg[qq][g * 4 + 0] += kf.x * qv[qq][dd];
                        sreg[qq][g * 4 + 1] += kf.y * qv[qq][dd];
                        sreg[qq][g * 4 + 2] += kf.z * qv[qq][dd];
                        sreg[qq][g * 4 + 3] += kf.w * qv[qq][dd];
                    }
                }
            }
        }

        #pragma unroll
        for (int qq = 0; qq < 2; ++qq) {
            float lmax = NEGINF; int lslot = 0;
            #pragma unroll
            for (int j = 0; j < 16; ++j)
                if (sreg[qq][j] > lmax) { lmax = sreg[qq][j]; lslot = j; }
            float t32 = __shfl(rv[qq], 31);
            for (int it = 0; it < 32; ++it) {
                float wm = lmax;
                #pragma unroll
                for (int off = 32; off; off >>= 1)
                    wm = fmaxf(wm, __shfl_xor(wm, off));
                if (wm <= t32) break;
                const unsigned long long bal = __ballot(lmax == wm);
                const int winner = __ffsll((unsigned long long)bal) - 1;
                const int wslot  = __shfl(lslot, winner);
                const int widx   = (s << 13) + (c << 10) + ((wslot >> 2) << 8)
                                 + (winner << 2) + (wslot & 3);
                const unsigned long long gb = __ballot((lane < K_) && (rv[qq] > wm));
                const int pos = __popcll(gb);
                const float sv = __shfl_up(rv[qq], 1);
                const int   si = __shfl_up(rid[qq], 1);
                if (lane > pos)       { rv[qq] = sv; rid[qq] = si; }
                else if (lane == pos) { rv[qq] = wm; rid[qq] = widx; }
                t32 = __shfl(rv[qq], 31);
                if (lane == winner) {
                    float nm = NEGINF; int ns = 0;
                    #pragma unroll
                    for (int j = 0; j < 16; ++j) {
                        const float vj = (j == lslot) ? NEGINF : sreg[qq][j];
                        sreg[qq][j] = vj;
                        if (vj > nm) { nm = vj; ns = j; }
                    }
                    lmax = nm; lslot = ns;
                }
            }
        }
        __syncthreads();
    }

    #pragma unroll
    for (int qq = 0; qq < 2; ++qq) {
        if (lane < K_) {
            const size_t qglob = (size_t)b * T_ + t0 + qq;
            cval[qglob * 64 + s * 32 + lane] = rv[qq];
            cidx[qglob * 64 + s * 32 + lane] = rid[qq];
        }
    }
}

// ---------------------------------------------------------------------------
// Merge 2x32 candidates -> top-32, softmax, V gather, gated combine (unchanged)
// ---------------------------------------------------------------------------
__global__ __launch_bounds__(256) void knn_merge_kernel(
    const float* __restrict__ cval, const int* __restrict__ cidx,
    const float* __restrict__ mem_vals, const float* __restrict__ outc,
    const float* __restrict__ gate, float* __restrict__ outp)
{
    __shared__ float wsel[4][K_];
    __shared__ int   isel[4][K_];
    const int tid = threadIdx.x;
    const int w = tid >> 6, lane = tid & 63;
    const int qglob = blockIdx.x * 4 + w;
    const int b = qglob >> 11;
    const float vv = cval[(size_t)qglob * 64 + lane];
    const int   ii = cidx[(size_t)qglob * 64 + lane];
    int rank = 0;
    for (int j = 0; j < 64; ++j) {
        const float ov = __shfl(vv, j);
        const int   oi = __shfl(ii, j);
        if (ov > vv || (ov == vv && oi < ii)) ++rank;
    }
    float m = vv;
    #pragma unroll
    for (int off = 32; off; off >>= 1) m = fmaxf(m, __shfl_xor(m, off));
    const float wgt = (rank < K_) ? __expf((vv - m) * SCALE) : 0.f;
    float ssum = wgt;
    #pragma unroll
    for (int off = 32; off; off >>= 1) ssum += __shfl_xor(ssum, off);
    if (rank < K_) { wsel[w][rank] = wgt; isel[w][rank] = ii; }
    __syncthreads();
    const float* vb = mem_vals + (size_t)b * N_ * D_;
    float acc = 0.f;
    #pragma unroll 4
    for (int j = 0; j < K_; ++j)
        acc += wsel[w][j] * vb[(size_t)isel[w][j] * D_ + lane];
    const float gv = gate[0];
    const size_t o = (size_t)qglob * D_ + lane;
    outp[o] = outc[o] * gv + (acc / ssum) * (1.f - gv);
}

extern "C" void kernel_launch(void* const* d_in, const int* in_sizes, int n_in,
                              void* d_out, int out_size, void* d_ws, size_t ws_size,
                              hipStream_t stream) {
    const float* x        = (const float*)d_in[0];
    const float* mem_keys = (const float*)d_in[1];
    const float* mem_vals = (const float*)d_in[2];
    const float* Wq       = (const float*)d_in[3];
    const float* bq       = (const float*)d_in[4];
    const float* Wk       = (const float*)d_in[5];
    const float* bk       = (const float*)d_in[6];
    const float* Wv       = (const float*)d_in[7];
    const float* bv       = (const float*)d_in[8];
    const float* gate     = (const float*)d_in[9];
    float* out = (float*)d_out;

    const size_t btd = (size_t)B_ * T_ * D_;   // 524288
    float* q    = (float*)d_ws;
    float* k    = q + btd;
    float* v    = k + btd;
    float* outc = v + btd;
    float* kT   = outc + btd;                  // [B][D][N] 16 MB
    float* cval = kT + (size_t)B_ * D_ * N_;   // [8192][64]
    int*   cidx = (int*)(cval + (size_t)B_ * T_ * 64);

    qkv_proj_kernel<<<B_ * T_ / 8, 192, 0, stream>>>(x, Wq, bq, Wk, bk, Wv, bv, q, k, v);
    transpose_keys_kernel<<<B_ * (N_ / 64), 256, 0, stream>>>(mem_keys, kT);
    causal_attn_kernel<<<B_ * T_, 256, 0, stream>>>(q, k, v, outc);
    knn_topk_kernel<<<(B_ * T_ / 8) * 2, 256, 0, stream>>>(q, kT, cval, cidx);
    knn_merge_kernel<<<(B_ * T_) / 4, 256, 0, stream>>>(cval, cidx, mem_vals, outc, gate, out);
}

// Round 5
// 1081.131 us; speedup vs baseline: 1.3297x; 1.0799x over previous
//
#include <hip/hip_runtime.h>
#include <math.h>

#define B_ 4
#define T_ 2048
#define C_ 1024
#define D_ 64
#define N_ 16384
#define K_ 32
#define SCALE 0.03125f   // 1/sqrt(1024)
#define NEGINF -3.402823e38f

// ---------------------------------------------------------------------------
// QKV projection (unchanged)
// ---------------------------------------------------------------------------
__global__ __launch_bounds__(192) void qkv_proj_kernel(
    const float* __restrict__ x,
    const float* __restrict__ Wq, const float* __restrict__ bq,
    const float* __restrict__ Wk, const float* __restrict__ bk,
    const float* __restrict__ Wv, const float* __restrict__ bvp,
    float* __restrict__ q, float* __restrict__ k, float* __restrict__ v)
{
    __shared__ float xs[8][C_];
    const int tid = threadIdx.x;
    const int row0 = blockIdx.x * 8;
    const float* xr = x + (size_t)row0 * C_;
    for (int i = tid; i < 8 * C_ / 4; i += 192)
        ((float4*)&xs[0][0])[i] = ((const float4*)xr)[i];
    __syncthreads();
    const int g = tid >> 6;
    const int d = tid & 63;
    const float* W    = (g == 0) ? Wq : (g == 1) ? Wk : Wv;
    const float* bias = (g == 0) ? bq : (g == 1) ? bk : bvp;
    float*       o    = (g == 0) ? q  : (g == 1) ? k  : v;
    float acc[8];
    const float b0 = bias[d];
    #pragma unroll
    for (int r = 0; r < 8; ++r) acc[r] = b0;
    #pragma unroll 4
    for (int c = 0; c < C_; ++c) {
        const float wv = W[c * D_ + d];
        #pragma unroll
        for (int r = 0; r < 8; ++r) acc[r] += xs[r][c] * wv;
    }
    #pragma unroll
    for (int r = 0; r < 8; ++r)
        o[(size_t)(row0 + r) * D_ + d] = acc[r];
}

// ---------------------------------------------------------------------------
// Transpose mem_keys [B][N][D] -> kT [B][D][N]  (unchanged)
// ---------------------------------------------------------------------------
__global__ __launch_bounds__(256) void transpose_keys_kernel(
    const float* __restrict__ keys, float* __restrict__ kT)
{
    __shared__ float tile[64][68];
    const int tid = threadIdx.x;
    const int b  = blockIdx.x >> 8;
    const int n0 = (blockIdx.x & 255) << 6;
    const float4* in4 = (const float4*)(keys + ((size_t)b * N_ + n0) * D_);
    #pragma unroll
    for (int p = 0; p < 4; ++p) {
        const int fi = tid + p * 256;
        const int n = fi >> 4, c4 = fi & 15;
        const float4 v = in4[n * 16 + c4];
        *(float4*)&tile[n][c4 * 4] = v;
    }
    __syncthreads();
    #pragma unroll
    for (int p = 0; p < 4; ++p) {
        const int fi = tid + p * 256;
        const int d = fi >> 4, n4 = fi & 15;
        float4 v;
        v.x = tile[n4 * 4 + 0][d];
        v.y = tile[n4 * 4 + 1][d];
        v.z = tile[n4 * 4 + 2][d];
        v.w = tile[n4 * 4 + 3][d];
        *(float4*)(kT + ((size_t)b * D_ + d) * N_ + n0 + n4 * 4) = v;
    }
}

// ---------------------------------------------------------------------------
// Causal attention (unchanged, round-1 version)
// ---------------------------------------------------------------------------
__global__ __launch_bounds__(256) void causal_attn_kernel(
    const float* __restrict__ q, const float* __restrict__ k,
    const float* __restrict__ v, float* __restrict__ outc)
{
    __shared__ float qs[D_];
    __shared__ float sc[T_];
    __shared__ float red[4][D_];
    __shared__ float redw[4];
    const int tid = threadIdx.x;
    const int b = blockIdx.x >> 11;
    const int t = blockIdx.x & (T_ - 1);
    if (tid < 64) qs[tid] = q[((size_t)b * T_ + t) * D_ + tid];
    __syncthreads();
    const int nS = t + 1;
    const float* kb = k + (size_t)b * T_ * D_;
    for (int s = tid; s < nS; s += 256) {
        const float* kr = kb + (size_t)s * D_;
        float dot = 0.f;
        #pragma unroll
        for (int d = 0; d < D_; d += 4) {
            const float4 k4 = *(const float4*)(kr + d);
            dot += qs[d]*k4.x + qs[d+1]*k4.y + qs[d+2]*k4.z + qs[d+3]*k4.w;
        }
        sc[s] = dot * SCALE;
    }
    __syncthreads();
    float lm = -3.0e38f;
    for (int s = tid; s < nS; s += 256) lm = fmaxf(lm, sc[s]);
    #pragma unroll
    for (int off = 32; off; off >>= 1) lm = fmaxf(lm, __shfl_xor(lm, off));
    if ((tid & 63) == 0) redw[tid >> 6] = lm;
    __syncthreads();
    const float m = fmaxf(fmaxf(redw[0], redw[1]), fmaxf(redw[2], redw[3]));
    __syncthreads();
    float ls = 0.f;
    for (int s = tid; s < nS; s += 256) {
        const float w = __expf(sc[s] - m);
        sc[s] = w;
        ls += w;
    }
    #pragma unroll
    for (int off = 32; off; off >>= 1) ls += __shfl_xor(ls, off);
    if ((tid & 63) == 0) redw[tid >> 6] = ls;
    __syncthreads();
    const float l = redw[0] + redw[1] + redw[2] + redw[3];
    const int g = tid >> 6, d = tid & 63;
    const float* vb = v + (size_t)b * T_ * D_;
    float acc = 0.f;
    for (int s = g; s < nS; s += 4) acc += sc[s] * vb[(size_t)s * D_ + d];
    red[g][d] = acc;
    __syncthreads();
    if (g == 0)
        outc[((size_t)b * T_ + t) * D_ + d] =
            (red[0][d] + red[1][d] + red[2][d] + red[3][d]) / l;
}

// ---------------------------------------------------------------------------
// kNN v4: KS=1, waves independent (no barriers).  Chunk 0: butterfly-extract
// warmup builds exact top-32.  Chunks 1..15: candidate-stream — per-lane mask
// of scores > t32 (pure VALU), then one cheap sorted-insert per candidate
// (no butterfly, no rebuild).  Epilogue (softmax+V-gather+gate) fused.
// ---------------------------------------------------------------------------
__global__ __launch_bounds__(256) void knn_topk_kernel(
    const float* __restrict__ qg, const float* __restrict__ kT,
    const float* __restrict__ mem_vals, const float* __restrict__ outc,
    const float* __restrict__ gate, float* __restrict__ outp)
{
    __shared__ float q_lds[4][2][64];
    const int tid = threadIdx.x;
    const int w = tid >> 6, lane = tid & 63;
    const int bid = blockIdx.x;
    const int b  = (bid & 7) >> 1;                  // batch -> XCD pair
    const int qt = ((bid >> 3) << 1) | (bid & 1);   // 0..255
    const int t0 = qt * 8 + w * 2;

    // per-wave private q staging (same-wave write->read, no barrier needed)
    #pragma unroll
    for (int qq = 0; qq < 2; ++qq)
        q_lds[w][qq][lane] = qg[((size_t)(b * T_ + t0 + qq)) * D_ + lane];

    const float4* kT4 = (const float4*)(kT + (size_t)b * D_ * N_);

    float rv[2];  int rid_[2];  float t32[2];
    rv[0] = rv[1] = NEGINF;
    rid_[0] = rid_[1] = 0x7fffffff;
    t32[0] = t32[1] = NEGINF;

    for (int c = 0; c < 16; ++c) {
        // ---- scores for chunk c: lane covers keys c*1024 + g*256 + lane*4 + j
        float sreg[2][16];
        #pragma unroll
        for (int qq = 0; qq < 2; ++qq)
            #pragma unroll
            for (int j = 0; j < 16; ++j) sreg[qq][j] = 0.f;

        for (int dt = 0; dt < 8; ++dt) {
            float qv[2][8];
            #pragma unroll
            for (int qq = 0; qq < 2; ++qq)
                #pragma unroll
                for (int dd = 0; dd < 8; ++dd)
                    qv[qq][dd] = q_lds[w][qq][dt * 8 + dd];
            #pragma unroll
            for (int g = 0; g < 4; ++g) {
                #pragma unroll
                for (int dd = 0; dd < 8; ++dd) {
                    const float4 kf =
                        kT4[(size_t)(dt * 8 + dd) * (N_ / 4) + c * 256 + g * 64 + lane];
                    #pragma unroll
                    for (int qq = 0; qq < 2; ++qq) {
                        sreg[qq][g * 4 + 0] += kf.x * qv[qq][dd];
                        sreg[qq][g * 4 + 1] += kf.y * qv[qq][dd];
                        sreg[qq][g * 4 + 2] += kf.z * qv[qq][dd];
                        sreg[qq][g * 4 + 3] += kf.w * qv[qq][dd];
                    }
                }
            }
        }

        if (c == 0) {
            // ---- warmup: 32 butterfly extractions build exact sorted top-32
            #pragma unroll
            for (int qq = 0; qq < 2; ++qq) {
                float lmax = NEGINF; int lslot = 0;
                #pragma unroll
                for (int j = 0; j < 16; ++j)
                    if (sreg[qq][j] > lmax) { lmax = sreg[qq][j]; lslot = j; }
                for (int it = 0; it < 32; ++it) {
                    float wm = lmax;
                    #pragma unroll
                    for (int off = 32; off; off >>= 1)
                        wm = fmaxf(wm, __shfl_xor(wm, off));
                    const unsigned long long bal = __ballot(lmax == wm);
                    const int winner = __ffsll((unsigned long long)bal) - 1;
                    const int wslot  = __shfl(lslot, winner);
                    const int widx   = ((wslot >> 2) << 8) + (winner << 2) + (wslot & 3);
                    const unsigned long long gb = __ballot((lane < K_) && (rv[qq] > wm));
                    const int pos = __popcll(gb);
                    const float sv = __shfl_up(rv[qq], 1);
                    const int   si = __shfl_up(rid_[qq], 1);
                    if (lane > pos)       { rv[qq] = sv; rid_[qq] = si; }
                    else if (lane == pos) { rv[qq] = wm; rid_[qq] = widx; }
                    if (lane == winner) {
                        float nm = NEGINF; int ns = 0;
                        #pragma unroll
                        for (int j = 0; j < 16; ++j) {
                            const float vj = (j == lslot) ? NEGINF : sreg[qq][j];
                            sreg[qq][j] = vj;
                            if (vj > nm) { nm = vj; ns = j; }
                        }
                        lmax = nm; lslot = ns;
                    }
                }
                t32[qq] = __shfl(rv[qq], 31);
            }
        } else {
            // ---- candidate-stream: rare inserts, short dependency chains
            #pragma unroll
            for (int qq = 0; qq < 2; ++qq) {
                unsigned int mask = 0u;
                #pragma unroll
                for (int j = 0; j < 16; ++j)
                    mask |= (sreg[qq][j] > t32[qq]) ? (1u << j) : 0u;
                while (true) {
                    const unsigned long long bb = __ballot(mask != 0u);
                    if (!bb) break;
                    const int L  = __ffsll(bb) - 1;
                    const unsigned int mL = (unsigned int)__shfl((int)mask, L);
                    const int j  = __ffs(mL) - 1;
                    // every lane selects its own sreg[qq][j] (static unroll),
                    // then broadcast winner's value
                    float xl = sreg[qq][0];
                    #pragma unroll
                    for (int jj = 1; jj < 16; ++jj)
                        xl = (j == jj) ? sreg[qq][jj] : xl;
                    const float xv = __shfl(xl, L);
                    const int   xi = (c << 10) + ((j >> 2) << 8) + (L << 2) + (j & 3);
                    if (lane == L) mask &= ~(1u << j);
                    if (xv > t32[qq]) {   // may be stale; uniform condition
                        const unsigned long long gb =
                            __ballot((lane < K_) && (rv[qq] > xv));
                        const int pos = __popcll(gb);
                        const float sv = __shfl_up(rv[qq], 1);
                        const int   si = __shfl_up(rid_[qq], 1);
                        if (lane > pos)       { rv[qq] = sv; rid_[qq] = si; }
                        else if (lane == pos) { rv[qq] = xv; rid_[qq] = xi; }
                        t32[qq] = __shfl(rv[qq], 31);
                    }
                }
            }
        }
    }

    // ---- epilogue: softmax over top-32, gather V, gated combine
    const float gv = gate[0];
    const float* vb = mem_vals + (size_t)b * N_ * D_;
    #pragma unroll
    for (int qq = 0; qq < 2; ++qq) {
        const float m = __shfl(rv[qq], 0);
        float wgt = (lane < K_) ? __expf((rv[qq] - m) * SCALE) : 0.f;
        float ssum = wgt;
        #pragma unroll
        for (int off = 32; off; off >>= 1) ssum += __shfl_xor(ssum, off);
        float acc = 0.f;
        for (int i = 0; i < K_; ++i) {
            const float wi = __shfl(wgt, i);
            const int   ii = __shfl(rid_[qq], i);
            acc += wi * vb[(size_t)ii * D_ + lane];
        }
        const size_t o = ((size_t)(b * T_ + t0 + qq)) * D_ + lane;
        outp[o] = outc[o] * gv + (acc / ssum) * (1.f - gv);
    }
}

extern "C" void kernel_launch(void* const* d_in, const int* in_sizes, int n_in,
                              void* d_out, int out_size, void* d_ws, size_t ws_size,
                              hipStream_t stream) {
    const float* x        = (const float*)d_in[0];
    const float* mem_keys = (const float*)d_in[1];
    const float* mem_vals = (const float*)d_in[2];
    const float* Wq       = (const float*)d_in[3];
    const float* bq       = (const float*)d_in[4];
    const float* Wk       = (const float*)d_in[5];
    const float* bk       = (const float*)d_in[6];
    const float* Wv       = (const float*)d_in[7];
    const float* bv       = (const float*)d_in[8];
    const float* gate     = (const float*)d_in[9];
    float* out = (float*)d_out;

    const size_t btd = (size_t)B_ * T_ * D_;   // 524288
    float* q    = (float*)d_ws;
    float* k    = q + btd;
    float* v    = k + btd;
    float* outc = v + btd;
    float* kT   = outc + btd;                  // [B][D][N] 16 MB

    qkv_proj_kernel<<<B_ * T_ / 8, 192, 0, stream>>>(x, Wq, bq, Wk, bk, Wv, bv, q, k, v);
    transpose_keys_kernel<<<B_ * (N_ / 64), 256, 0, stream>>>(mem_keys, kT);
    causal_attn_kernel<<<B_ * T_, 256, 0, stream>>>(q, k, v, outc);
    knn_topk_kernel<<<(B_ * T_) / 8, 256, 0, stream>>>(q, kT, mem_vals, outc, gate, out);
}

// Round 6
// 1081.069 us; speedup vs baseline: 1.3298x; 1.0001x over previous
//
#include <hip/hip_runtime.h>
#include <math.h>

#define B_ 4
#define T_ 2048
#define C_ 1024
#define D_ 64
#define N_ 16384
#define K_ 32
#define SCALE 0.03125f   // 1/sqrt(1024)
#define NEGINF -3.402823e38f

// ---------------------------------------------------------------------------
// QKV projection (unchanged)
// ---------------------------------------------------------------------------
__global__ __launch_bounds__(192) void qkv_proj_kernel(
    const float* __restrict__ x,
    const float* __restrict__ Wq, const float* __restrict__ bq,
    const float* __restrict__ Wk, const float* __restrict__ bk,
    const float* __restrict__ Wv, const float* __restrict__ bvp,
    float* __restrict__ q, float* __restrict__ k, float* __restrict__ v)
{
    __shared__ float xs[8][C_];
    const int tid = threadIdx.x;
    const int row0 = blockIdx.x * 8;
    const float* xr = x + (size_t)row0 * C_;
    for (int i = tid; i < 8 * C_ / 4; i += 192)
        ((float4*)&xs[0][0])[i] = ((const float4*)xr)[i];
    __syncthreads();
    const int g = tid >> 6;
    const int d = tid & 63;
    const float* W    = (g == 0) ? Wq : (g == 1) ? Wk : Wv;
    const float* bias = (g == 0) ? bq : (g == 1) ? bk : bvp;
    float*       o    = (g == 0) ? q  : (g == 1) ? k  : v;
    float acc[8];
    const float b0 = bias[d];
    #pragma unroll
    for (int r = 0; r < 8; ++r) acc[r] = b0;
    #pragma unroll 4
    for (int c = 0; c < C_; ++c) {
        const float wv = W[c * D_ + d];
        #pragma unroll
        for (int r = 0; r < 8; ++r) acc[r] += xs[r][c] * wv;
    }
    #pragma unroll
    for (int r = 0; r < 8; ++r)
        o[(size_t)(row0 + r) * D_ + d] = acc[r];
}

// ---------------------------------------------------------------------------
// Transpose mem_keys [B][N][D] -> kT [B][D][N]  (unchanged)
// ---------------------------------------------------------------------------
__global__ __launch_bounds__(256) void transpose_keys_kernel(
    const float* __restrict__ keys, float* __restrict__ kT)
{
    __shared__ float tile[64][68];
    const int tid = threadIdx.x;
    const int b  = blockIdx.x >> 8;
    const int n0 = (blockIdx.x & 255) << 6;
    const float4* in4 = (const float4*)(keys + ((size_t)b * N_ + n0) * D_);
    #pragma unroll
    for (int p = 0; p < 4; ++p) {
        const int fi = tid + p * 256;
        const int n = fi >> 4, c4 = fi & 15;
        const float4 v = in4[n * 16 + c4];
        *(float4*)&tile[n][c4 * 4] = v;
    }
    __syncthreads();
    #pragma unroll
    for (int p = 0; p < 4; ++p) {
        const int fi = tid + p * 256;
        const int d = fi >> 4, n4 = fi & 15;
        float4 v;
        v.x = tile[n4 * 4 + 0][d];
        v.y = tile[n4 * 4 + 1][d];
        v.z = tile[n4 * 4 + 2][d];
        v.w = tile[n4 * 4 + 3][d];
        *(float4*)(kT + ((size_t)b * D_ + d) * N_ + n0 + n4 * 4) = v;
    }
}

// ---------------------------------------------------------------------------
// Causal attention (unchanged, round-1 version)
// ---------------------------------------------------------------------------
__global__ __launch_bounds__(256) void causal_attn_kernel(
    const float* __restrict__ q, const float* __restrict__ k,
    const float* __restrict__ v, float* __restrict__ outc)
{
    __shared__ float qs[D_];
    __shared__ float sc[T_];
    __shared__ float red[4][D_];
    __shared__ float redw[4];
    const int tid = threadIdx.x;
    const int b = blockIdx.x >> 11;
    const int t = blockIdx.x & (T_ - 1);
    if (tid < 64) qs[tid] = q[((size_t)b * T_ + t) * D_ + tid];
    __syncthreads();
    const int nS = t + 1;
    const float* kb = k + (size_t)b * T_ * D_;
    for (int s = tid; s < nS; s += 256) {
        const float* kr = kb + (size_t)s * D_;
        float dot = 0.f;
        #pragma unroll
        for (int d = 0; d < D_; d += 4) {
            const float4 k4 = *(const float4*)(kr + d);
            dot += qs[d]*k4.x + qs[d+1]*k4.y + qs[d+2]*k4.z + qs[d+3]*k4.w;
        }
        sc[s] = dot * SCALE;
    }
    __syncthreads();
    float lm = -3.0e38f;
    for (int s = tid; s < nS; s += 256) lm = fmaxf(lm, sc[s]);
    #pragma unroll
    for (int off = 32; off; off >>= 1) lm = fmaxf(lm, __shfl_xor(lm, off));
    if ((tid & 63) == 0) redw[tid >> 6] = lm;
    __syncthreads();
    const float m = fmaxf(fmaxf(redw[0], redw[1]), fmaxf(redw[2], redw[3]));
    __syncthreads();
    float ls = 0.f;
    for (int s = tid; s < nS; s += 256) {
        const float w = __expf(sc[s] - m);
        sc[s] = w;
        ls += w;
    }
    #pragma unroll
    for (int off = 32; off; off >>= 1) ls += __shfl_xor(ls, off);
    if ((tid & 63) == 0) redw[tid >> 6] = ls;
    __syncthreads();
    const float l = redw[0] + redw[1] + redw[2] + redw[3];
    const int g = tid >> 6, d = tid & 63;
    const float* vb = v + (size_t)b * T_ * D_;
    float acc = 0.f;
    for (int s = g; s < nS; s += 4) acc += sc[s] * vb[(size_t)s * D_ + d];
    red[g][d] = acc;
    __syncthreads();
    if (g == 0)
        outc[((size_t)b * T_ + t) * D_ + d] =
            (red[0][d] + red[1][d] + red[2][d] + red[3][d]) / l;
}

// ---------------------------------------------------------------------------
// kNN v5: LDS-staged key chunks.  Block = 4 waves, TQ=16 queries (4/wave).
// Per 256-key chunk: stage [64 dims][256 keys] tile (64 KB) once per block,
// all waves score from LDS (ds_read_b128, conflict-free row reads).
// Selection: chunk-0 butterfly warmup -> exact top-32; later chunks use the
// round-4 candidate-stream (mask of scores > t32, cheap sorted inserts).
// Epilogue fused.  Cuts per-CU global traffic 8x vs round 4.
// ---------------------------------------------------------------------------
__global__ __launch_bounds__(256) void knn_topk_kernel(
    const float* __restrict__ qg, const float* __restrict__ kT,
    const float* __restrict__ mem_vals, const float* __restrict__ outc,
    const float* __restrict__ gate, float* __restrict__ outp)
{
    __shared__ float sk[D_][256];        // 64 KB key tile
    __shared__ float q_lds[4][4][D_];    // 4 KB
    const int tid = threadIdx.x;
    const int w = tid >> 6, lane = tid & 63;
    const int bid = blockIdx.x;                     // 512 blocks
    const int b  = (bid & 7) >> 1;                  // batch -> XCD pair
    const int qt = ((bid >> 3) << 1) | (bid & 1);   // 0..127
    const int t0 = qt * 16 + w * 4;                 // 4 queries per wave

    #pragma unroll
    for (int qq = 0; qq < 4; ++qq)
        q_lds[w][qq][lane] = qg[((size_t)(b * T_ + t0 + qq)) * D_ + lane];

    const float4* kT4 = (const float4*)(kT + (size_t)b * D_ * N_);

    float rv[4];  int rid_[4];  float t32[4];
    #pragma unroll
    for (int qq = 0; qq < 4; ++qq) {
        rv[qq] = NEGINF; rid_[qq] = 0x7fffffff; t32[qq] = NEGINF;
    }

    for (int c = 0; c < 64; ++c) {
        __syncthreads();   // previous chunk's compute done before overwrite
        // ---- stage keys [64 dims][256 keys] ; wave-contiguous, coalesced
        #pragma unroll
        for (int r = 0; r < 16; ++r) {
            const int flat = r * 256 + tid;        // 0..4095
            const int dim = flat >> 6, k4 = flat & 63;
            *(float4*)&sk[dim][k4 * 4] =
                kT4[(size_t)(b * D_ + dim) * 0 + (size_t)dim * (N_ / 4) + c * 64 + k4];
        }
        __syncthreads();

        // ---- score 256 keys x 4 queries; lane owns keys c*256 + lane*4 + j
        float s4[4][4];
        #pragma unroll
        for (int qq = 0; qq < 4; ++qq)
            #pragma unroll
            for (int j = 0; j < 4; ++j) s4[qq][j] = 0.f;

        #pragma unroll 4
        for (int dg = 0; dg < 16; ++dg) {
            float4 q4[4];
            #pragma unroll
            for (int qq = 0; qq < 4; ++qq)
                q4[qq] = *(const float4*)&q_lds[w][qq][dg * 4];
            #pragma unroll
            for (int dd = 0; dd < 4; ++dd) {
                const float4 kf = *(const float4*)&sk[dg * 4 + dd][lane * 4];
                #pragma unroll
                for (int qq = 0; qq < 4; ++qq) {
                    const float qv = (dd == 0) ? q4[qq].x : (dd == 1) ? q4[qq].y
                                   : (dd == 2) ? q4[qq].z : q4[qq].w;
                    s4[qq][0] += kf.x * qv;
                    s4[qq][1] += kf.y * qv;
                    s4[qq][2] += kf.z * qv;
                    s4[qq][3] += kf.w * qv;
                }
            }
        }

        if (c == 0) {
            // ---- warmup: exact sorted top-32 of first 256 keys
            #pragma unroll
            for (int qq = 0; qq < 4; ++qq) {
                float lmax = NEGINF; int lslot = 0;
                #pragma unroll
                for (int j = 0; j < 4; ++j)
                    if (s4[qq][j] > lmax) { lmax = s4[qq][j]; lslot = j; }
                for (int it = 0; it < 32; ++it) {
                    float wm = lmax;
                    #pragma unroll
                    for (int off = 32; off; off >>= 1)
                        wm = fmaxf(wm, __shfl_xor(wm, off));
                    const unsigned long long bal = __ballot(lmax == wm);
                    const int winner = __ffsll((unsigned long long)bal) - 1;
                    const int wslot  = __shfl(lslot, winner);
                    const int widx   = (winner << 2) + (wslot & 3);
                    const unsigned long long gb = __ballot((lane < K_) && (rv[qq] > wm));
                    const int pos = __popcll(gb);
                    const float sv = __shfl_up(rv[qq], 1);
                    const int   si = __shfl_up(rid_[qq], 1);
                    if (lane > pos)       { rv[qq] = sv; rid_[qq] = si; }
                    else if (lane == pos) { rv[qq] = wm; rid_[qq] = widx; }
                    if (lane == winner) {
                        float nm = NEGINF; int ns = 0;
                        #pragma unroll
                        for (int j = 0; j < 4; ++j) {
                            const float vj = (j == lslot) ? NEGINF : s4[qq][j];
                            s4[qq][j] = vj;
                            if (vj > nm) { nm = vj; ns = j; }
                        }
                        lmax = nm; lslot = ns;
                    }
                }
                t32[qq] = __shfl(rv[qq], 31);
            }
        } else {
            // ---- candidate-stream inserts
            #pragma unroll
            for (int qq = 0; qq < 4; ++qq) {
                unsigned int mask = 0u;
                #pragma unroll
                for (int j = 0; j < 4; ++j)
                    mask |= (s4[qq][j] > t32[qq]) ? (1u << j) : 0u;
                while (true) {
                    const unsigned long long bb = __ballot(mask != 0u);
                    if (!bb) break;
                    const int L  = __ffsll(bb) - 1;
                    const unsigned int mL = (unsigned int)__shfl((int)mask, L);
                    const int j  = __ffs(mL) - 1;
                    float xl = s4[qq][0];
                    #pragma unroll
                    for (int jj = 1; jj < 4; ++jj)
                        xl = (j == jj) ? s4[qq][jj] : xl;
                    const float xv = __shfl(xl, L);
                    const int   xi = (c << 8) + (L << 2) + j;
                    if (lane == L) mask &= ~(1u << j);
                    if (xv > t32[qq]) {
                        const unsigned long long gb =
                            __ballot((lane < K_) && (rv[qq] > xv));
                        const int pos = __popcll(gb);
                        const float sv = __shfl_up(rv[qq], 1);
                        const int   si = __shfl_up(rid_[qq], 1);
                        if (lane > pos)       { rv[qq] = sv; rid_[qq] = si; }
                        else if (lane == pos) { rv[qq] = xv; rid_[qq] = xi; }
                        t32[qq] = __shfl(rv[qq], 31);
                    }
                }
            }
        }
    }

    // ---- epilogue: softmax over top-32, gather V, gated combine
    const float gv = gate[0];
    const float* vb = mem_vals + (size_t)b * N_ * D_;
    #pragma unroll
    for (int qq = 0; qq < 4; ++qq) {
        const float m = __shfl(rv[qq], 0);
        float wgt = (lane < K_) ? __expf((rv[qq] - m) * SCALE) : 0.f;
        float ssum = wgt;
        #pragma unroll
        for (int off = 32; off; off >>= 1) ssum += __shfl_xor(ssum, off);
        float acc = 0.f;
        for (int i = 0; i < K_; ++i) {
            const float wi = __shfl(wgt, i);
            const int   ii = __shfl(rid_[qq], i);
            acc += wi * vb[(size_t)ii * D_ + lane];
        }
        const size_t o = ((size_t)(b * T_ + t0 + qq)) * D_ + lane;
        outp[o] = outc[o] * gv + (acc / ssum) * (1.f - gv);
    }
}

extern "C" void kernel_launch(void* const* d_in, const int* in_sizes, int n_in,
                              void* d_out, int out_size, void* d_ws, size_t ws_size,
                              hipStream_t stream) {
    const float* x        = (const float*)d_in[0];
    const float* mem_keys = (const float*)d_in[1];
    const float* mem_vals = (const float*)d_in[2];
    const float* Wq       = (const float*)d_in[3];
    const float* bq       = (const float*)d_in[4];
    const float* Wk       = (const float*)d_in[5];
    const float* bk       = (const float*)d_in[6];
    const float* Wv       = (const float*)d_in[7];
    const float* bv       = (const float*)d_in[8];
    const float* gate     = (const float*)d_in[9];
    float* out = (float*)d_out;

    const size_t btd = (size_t)B_ * T_ * D_;   // 524288
    float* q    = (float*)d_ws;
    float* k    = q + btd;
    float* v    = k + btd;
    float* outc = v + btd;
    float* kT   = outc + btd;                  // [B][D][N] 16 MB

    qkv_proj_kernel<<<B_ * T_ / 8, 192, 0, stream>>>(x, Wq, bq, Wk, bk, Wv, bv, q, k, v);
    transpose_keys_kernel<<<B_ * (N_ / 64), 256, 0, stream>>>(mem_keys, kT);
    causal_attn_kernel<<<B_ * T_, 256, 0, stream>>>(q, k, v, outc);
    knn_topk_kernel<<<(B_ * T_) / 16, 256, 0, stream>>>(q, kT, mem_vals, outc, gate, out);
}

// Round 7
// 893.708 us; speedup vs baseline: 1.6086x; 1.2096x over previous
//
#include <hip/hip_runtime.h>
#include <math.h>

#define B_ 4
#define T_ 2048
#define C_ 1024
#define D_ 64
#define N_ 16384
#define K_ 32
#define SCALE 0.03125f   // 1/sqrt(1024)
#define NEGINF -3.402823e38f

typedef __attribute__((ext_vector_type(8))) short short8_t;  // 8 bf16 (4 VGPRs)
typedef __attribute__((ext_vector_type(4))) float f32x4;

__device__ __forceinline__ unsigned short f2bf(float x) {
    union { float f; unsigned u; } a; a.f = x;
    const unsigned r = a.u + 0x7fffu + ((a.u >> 16) & 1u);   // round-nearest-even
    return (unsigned short)(r >> 16);
}
__device__ __forceinline__ float bf2f(unsigned short h) {
    union { unsigned u; float f; } a; a.u = ((unsigned)h) << 16;
    return a.f;
}

// ---------------------------------------------------------------------------
// QKV projection (unchanged)
// ---------------------------------------------------------------------------
__global__ __launch_bounds__(192) void qkv_proj_kernel(
    const float* __restrict__ x,
    const float* __restrict__ Wq, const float* __restrict__ bq,
    const float* __restrict__ Wk, const float* __restrict__ bk,
    const float* __restrict__ Wv, const float* __restrict__ bvp,
    float* __restrict__ q, float* __restrict__ k, float* __restrict__ v)
{
    __shared__ float xs[8][C_];
    const int tid = threadIdx.x;
    const int row0 = blockIdx.x * 8;
    const float* xr = x + (size_t)row0 * C_;
    for (int i = tid; i < 8 * C_ / 4; i += 192)
        ((float4*)&xs[0][0])[i] = ((const float4*)xr)[i];
    __syncthreads();
    const int g = tid >> 6;
    const int d = tid & 63;
    const float* W    = (g == 0) ? Wq : (g == 1) ? Wk : Wv;
    const float* bias = (g == 0) ? bq : (g == 1) ? bk : bvp;
    float*       o    = (g == 0) ? q  : (g == 1) ? k  : v;
    float acc[8];
    const float b0 = bias[d];
    #pragma unroll
    for (int r = 0; r < 8; ++r) acc[r] = b0;
    #pragma unroll 4
    for (int c = 0; c < C_; ++c) {
        const float wv = W[c * D_ + d];
        #pragma unroll
        for (int r = 0; r < 8; ++r) acc[r] += xs[r][c] * wv;
    }
    #pragma unroll
    for (int r = 0; r < 8; ++r)
        o[(size_t)(row0 + r) * D_ + d] = acc[r];
}

// ---------------------------------------------------------------------------
// Pack mem_keys into bf16 hi/lo MFMA B-fragment layout.
// khi/klo[b][ntile][kstep][lane][8]: lane&15 = key-in-tile, (lane>>4)*8+j = dim
// within kstep*32.  Main kernel then loads fragments with one coalesced 16B
// load per lane.
// ---------------------------------------------------------------------------
__global__ __launch_bounds__(256) void kfrag_prep_kernel(
    const float* __restrict__ keys, unsigned short* __restrict__ khi,
    unsigned short* __restrict__ klo)
{
    const int tid = threadIdx.x;
    const int lane = tid & 63;
    const int ks = (tid >> 6) & 1;
    const int b  = blockIdx.x >> 9;                         // 512 blocks/batch
    const int nt = ((blockIdx.x & 511) << 1) | (tid >> 7);  // 0..1023
    const int key = nt * 16 + (lane & 15);
    const float* src = keys + ((size_t)b * N_ + key) * D_ + ks * 32 + (lane >> 4) * 8;
    const size_t o = (((size_t)b * 1024 + nt) * 2 + ks) * 512 + (size_t)lane * 8;
    #pragma unroll
    for (int j = 0; j < 8; ++j) {
        const float xv = src[j];
        const unsigned short h = f2bf(xv);
        khi[o + j] = h;
        klo[o + j] = f2bf(xv - bf2f(h));
    }
}

// ---------------------------------------------------------------------------
// Causal attention (unchanged, round-1 version)
// ---------------------------------------------------------------------------
__global__ __launch_bounds__(256) void causal_attn_kernel(
    const float* __restrict__ q, const float* __restrict__ k,
    const float* __restrict__ v, float* __restrict__ outc)
{
    __shared__ float qs[D_];
    __shared__ float sc[T_];
    __shared__ float red[4][D_];
    __shared__ float redw[4];
    const int tid = threadIdx.x;
    const int b = blockIdx.x >> 11;
    const int t = blockIdx.x & (T_ - 1);
    if (tid < 64) qs[tid] = q[((size_t)b * T_ + t) * D_ + tid];
    __syncthreads();
    const int nS = t + 1;
    const float* kb = k + (size_t)b * T_ * D_;
    for (int s = tid; s < nS; s += 256) {
        const float* kr = kb + (size_t)s * D_;
        float dot = 0.f;
        #pragma unroll
        for (int d = 0; d < D_; d += 4) {
            const float4 k4 = *(const float4*)(kr + d);
            dot += qs[d]*k4.x + qs[d+1]*k4.y + qs[d+2]*k4.z + qs[d+3]*k4.w;
        }
        sc[s] = dot * SCALE;
    }
    __syncthreads();
    float lm = -3.0e38f;
    for (int s = tid; s < nS; s += 256) lm = fmaxf(lm, sc[s]);
    #pragma unroll
    for (int off = 32; off; off >>= 1) lm = fmaxf(lm, __shfl_xor(lm, off));
    if ((tid & 63) == 0) redw[tid >> 6] = lm;
    __syncthreads();
    const float m = fmaxf(fmaxf(redw[0], redw[1]), fmaxf(redw[2], redw[3]));
    __syncthreads();
    float ls = 0.f;
    for (int s = tid; s < nS; s += 256) {
        const float w = __expf(sc[s] - m);
        sc[s] = w;
        ls += w;
    }
    #pragma unroll
    for (int off = 32; off; off >>= 1) ls += __shfl_xor(ls, off);
    if ((tid & 63) == 0) redw[tid >> 6] = ls;
    __syncthreads();
    const float l = redw[0] + redw[1] + redw[2] + redw[3];
    const int g = tid >> 6, d = tid & 63;
    const float* vb = v + (size_t)b * T_ * D_;
    float acc = 0.f;
    for (int s = g; s < nS; s += 4) acc += sc[s] * vb[(size_t)s * D_ + d];
    red[g][d] = acc;
    __syncthreads();
    if (g == 0)
        outc[((size_t)b * T_ + t) * D_ + d] =
            (red[0][d] + red[1][d] + red[2][d] + red[3][d]) / l;
}

// ---------------------------------------------------------------------------
// kNN v6: MFMA scoring (bf16 hi/lo split, 3 passes -> fp32-accurate scores).
// Block = 4 waves, TQ=16 queries.  Per 256-key chunk: each wave scores 4
// 16x16 tiles (6 mfma each) -> scores to LDS [16q][256k]; barrier; each wave
// runs the proven candidate-stream selection for its 4 queries.  Epilogue
// (softmax over 32, V gather, gate) fused.
// ---------------------------------------------------------------------------
__global__ __launch_bounds__(256) void knn_mfma_kernel(
    const float* __restrict__ qg,
    const unsigned short* __restrict__ khi, const unsigned short* __restrict__ klo,
    const float* __restrict__ mem_vals, const float* __restrict__ outc,
    const float* __restrict__ gate, float* __restrict__ outp)
{
    __shared__ float sc_lds[16][256];   // 16 KB score tile
    const int tid = threadIdx.x;
    const int w = tid >> 6, lane = tid & 63;
    const int bid = blockIdx.x;                     // 512 blocks
    const int b  = (bid & 7) >> 1;                  // batch -> XCD pair
    const int qt = ((bid >> 3) << 1) | (bid & 1);   // 0..127
    const int t0 = qt * 16;

    // ---- build Q fragments (A-operand): row = t0+(lane&15), k = (lane>>4)*8+j
    short8_t qh[2], ql[2];
    {
        const int qrow = t0 + (lane & 15);
        const float* qs = qg + ((size_t)b * T_ + qrow) * D_ + (lane >> 4) * 8;
        #pragma unroll
        for (int ks2 = 0; ks2 < 2; ++ks2) {
            #pragma unroll
            for (int j = 0; j < 8; ++j) {
                const float xv = qs[ks2 * 32 + j];
                const unsigned short h = f2bf(xv);
                qh[ks2][j] = (short)h;
                ql[ks2][j] = (short)f2bf(xv - bf2f(h));
            }
        }
    }

    float rv[4];  int rid_[4];  float t32[4];
    #pragma unroll
    for (int qq = 0; qq < 4; ++qq) {
        rv[qq] = NEGINF; rid_[qq] = 0x7fffffff; t32[qq] = NEGINF;
    }

    for (int c = 0; c < 64; ++c) {
        if (c) __syncthreads();   // previous chunk's selection done

        // ---- score phase: wave w owns tiles w, w+4, w+8, w+12
        #pragma unroll
        for (int tt = 0; tt < 4; ++tt) {
            const int tl = w + 4 * tt;
            const size_t kb = (((size_t)b * 1024 + (size_t)c * 16 + tl) * 2) * 512
                            + (size_t)lane * 8;
            const short8_t kh0 = *(const short8_t*)(khi + kb);
            const short8_t kh1 = *(const short8_t*)(khi + kb + 512);
            const short8_t kl0 = *(const short8_t*)(klo + kb);
            const short8_t kl1 = *(const short8_t*)(klo + kb + 512);
            f32x4 acc = {0.f, 0.f, 0.f, 0.f};
            acc = __builtin_amdgcn_mfma_f32_16x16x32_bf16(qh[0], kh0, acc, 0, 0, 0);
            acc = __builtin_amdgcn_mfma_f32_16x16x32_bf16(qh[1], kh1, acc, 0, 0, 0);
            acc = __builtin_amdgcn_mfma_f32_16x16x32_bf16(qh[0], kl0, acc, 0, 0, 0);
            acc = __builtin_amdgcn_mfma_f32_16x16x32_bf16(qh[1], kl1, acc, 0, 0, 0);
            acc = __builtin_amdgcn_mfma_f32_16x16x32_bf16(ql[0], kh0, acc, 0, 0, 0);
            acc = __builtin_amdgcn_mfma_f32_16x16x32_bf16(ql[1], kh1, acc, 0, 0, 0);
            // C layout: col = lane&15 (key), row = (lane>>4)*4 + reg (query)
            const int qrow4 = (lane >> 4) * 4;
            const int col = tl * 16 + (lane & 15);
            #pragma unroll
            for (int r = 0; r < 4; ++r) sc_lds[qrow4 + r][col] = acc[r];
        }
        __syncthreads();

        // ---- selection phase: wave w selects for queries t0 + 4w .. +3
        float s4[4][4];
        #pragma unroll
        for (int qq = 0; qq < 4; ++qq)
            *(float4*)(&s4[qq][0]) = *(const float4*)&sc_lds[w * 4 + qq][lane * 4];

        if (c == 0) {
            // warmup: exact sorted top-32 of first 256 keys
            #pragma unroll
            for (int qq = 0; qq < 4; ++qq) {
                float lmax = NEGINF; int lslot = 0;
                #pragma unroll
                for (int j = 0; j < 4; ++j)
                    if (s4[qq][j] > lmax) { lmax = s4[qq][j]; lslot = j; }
                for (int it = 0; it < 32; ++it) {
                    float wm = lmax;
                    #pragma unroll
                    for (int off = 32; off; off >>= 1)
                        wm = fmaxf(wm, __shfl_xor(wm, off));
                    const unsigned long long bal = __ballot(lmax == wm);
                    const int winner = __ffsll((unsigned long long)bal) - 1;
                    const int wslot  = __shfl(lslot, winner);
                    const int widx   = (winner << 2) + (wslot & 3);
                    const unsigned long long gb = __ballot((lane < K_) && (rv[qq] > wm));
                    const int pos = __popcll(gb);
                    const float sv = __shfl_up(rv[qq], 1);
                    const int   si = __shfl_up(rid_[qq], 1);
                    if (lane > pos)       { rv[qq] = sv; rid_[qq] = si; }
                    else if (lane == pos) { rv[qq] = wm; rid_[qq] = widx; }
                    if (lane == winner) {
                        float nm = NEGINF; int ns = 0;
                        #pragma unroll
                        for (int j = 0; j < 4; ++j) {
                            const float vj = (j == lslot) ? NEGINF : s4[qq][j];
                            s4[qq][j] = vj;
                            if (vj > nm) { nm = vj; ns = j; }
                        }
                        lmax = nm; lslot = ns;
                    }
                }
                t32[qq] = __shfl(rv[qq], 31);
            }
        } else {
            // candidate-stream inserts
            #pragma unroll
            for (int qq = 0; qq < 4; ++qq) {
                unsigned int mask = 0u;
                #pragma unroll
                for (int j = 0; j < 4; ++j)
                    mask |= (s4[qq][j] > t32[qq]) ? (1u << j) : 0u;
                while (true) {
                    const unsigned long long bb = __ballot(mask != 0u);
                    if (!bb) break;
                    const int L  = __ffsll(bb) - 1;
                    const unsigned int mL = (unsigned int)__shfl((int)mask, L);
                    const int j  = __ffs(mL) - 1;
                    float xl = s4[qq][0];
                    #pragma unroll
                    for (int jj = 1; jj < 4; ++jj)
                        xl = (j == jj) ? s4[qq][jj] : xl;
                    const float xv = __shfl(xl, L);
                    const int   xi = (c << 8) + (L << 2) + j;
                    if (lane == L) mask &= ~(1u << j);
                    if (xv > t32[qq]) {
                        const unsigned long long gb =
                            __ballot((lane < K_) && (rv[qq] > xv));
                        const int pos = __popcll(gb);
                        const float sv = __shfl_up(rv[qq], 1);
                        const int   si = __shfl_up(rid_[qq], 1);
                        if (lane > pos)       { rv[qq] = sv; rid_[qq] = si; }
                        else if (lane == pos) { rv[qq] = xv; rid_[qq] = xi; }
                        t32[qq] = __shfl(rv[qq], 31);
                    }
                }
            }
        }
    }

    // ---- epilogue: softmax over top-32, gather V, gated combine
    const float gv = gate[0];
    const float* vb = mem_vals + (size_t)b * N_ * D_;
    #pragma unroll
    for (int qq = 0; qq < 4; ++qq) {
        const float m = __shfl(rv[qq], 0);
        float wgt = (lane < K_) ? __expf((rv[qq] - m) * SCALE) : 0.f;
        float ssum = wgt;
        #pragma unroll
        for (int off = 32; off; off >>= 1) ssum += __shfl_xor(ssum, off);
        float acc = 0.f;
        for (int i = 0; i < K_; ++i) {
            const float wi = __shfl(wgt, i);
            const int   ii = __shfl(rid_[qq], i);
            acc += wi * vb[(size_t)ii * D_ + lane];
        }
        const size_t o = ((size_t)(b * T_ + t0 + w * 4 + qq)) * D_ + lane;
        outp[o] = outc[o] * gv + (acc / ssum) * (1.f - gv);
    }
}

extern "C" void kernel_launch(void* const* d_in, const int* in_sizes, int n_in,
                              void* d_out, int out_size, void* d_ws, size_t ws_size,
                              hipStream_t stream) {
    const float* x        = (const float*)d_in[0];
    const float* mem_keys = (const float*)d_in[1];
    const float* mem_vals = (const float*)d_in[2];
    const float* Wq       = (const float*)d_in[3];
    const float* bq       = (const float*)d_in[4];
    const float* Wk       = (const float*)d_in[5];
    const float* bk       = (const float*)d_in[6];
    const float* Wv       = (const float*)d_in[7];
    const float* bv       = (const float*)d_in[8];
    const float* gate     = (const float*)d_in[9];
    float* out = (float*)d_out;

    const size_t btd = (size_t)B_ * T_ * D_;   // 524288
    float* q    = (float*)d_ws;
    float* k    = q + btd;
    float* v    = k + btd;
    float* outc = v + btd;
    unsigned short* khi = (unsigned short*)(outc + btd);   // [B][1024][2][64][8] bf16
    unsigned short* klo = khi + (size_t)B_ * N_ * D_;

    qkv_proj_kernel<<<B_ * T_ / 8, 192, 0, stream>>>(x, Wq, bq, Wk, bk, Wv, bv, q, k, v);
    kfrag_prep_kernel<<<B_ * 512, 256, 0, stream>>>(mem_keys, khi, klo);
    causal_attn_kernel<<<B_ * T_, 256, 0, stream>>>(q, k, v, outc);
    knn_mfma_kernel<<<(B_ * T_) / 16, 256, 0, stream>>>(q, khi, klo, mem_vals, outc, gate, out);
}

// Round 8
// 474.723 us; speedup vs baseline: 3.0283x; 1.8826x over previous
//
#include <hip/hip_runtime.h>
#include <math.h>

#define B_ 4
#define T_ 2048
#define C_ 1024
#define D_ 64
#define N_ 16384
#define K_ 32
#define SCALE 0.03125f   // 1/sqrt(1024)
#define NEGINF -3.402823e38f

typedef __attribute__((ext_vector_type(8))) short short8_t;  // 8 bf16 (4 VGPRs)
typedef __attribute__((ext_vector_type(4))) float f32x4;

__device__ __forceinline__ unsigned short f2bf(float x) {
    union { float f; unsigned u; } a; a.f = x;
    const unsigned r = a.u + 0x7fffu + ((a.u >> 16) & 1u);   // round-nearest-even
    return (unsigned short)(r >> 16);
}
__device__ __forceinline__ float bf2f(unsigned short h) {
    union { unsigned u; float f; } a; a.u = ((unsigned)h) << 16;
    return a.f;
}

// ---------------------------------------------------------------------------
// QKV projection (unchanged)
// ---------------------------------------------------------------------------
__global__ __launch_bounds__(192) void qkv_proj_kernel(
    const float* __restrict__ x,
    const float* __restrict__ Wq, const float* __restrict__ bq,
    const float* __restrict__ Wk, const float* __restrict__ bk,
    const float* __restrict__ Wv, const float* __restrict__ bvp,
    float* __restrict__ q, float* __restrict__ k, float* __restrict__ v)
{
    __shared__ float xs[8][C_];
    const int tid = threadIdx.x;
    const int row0 = blockIdx.x * 8;
    const float* xr = x + (size_t)row0 * C_;
    for (int i = tid; i < 8 * C_ / 4; i += 192)
        ((float4*)&xs[0][0])[i] = ((const float4*)xr)[i];
    __syncthreads();
    const int g = tid >> 6;
    const int d = tid & 63;
    const float* W    = (g == 0) ? Wq : (g == 1) ? Wk : Wv;
    const float* bias = (g == 0) ? bq : (g == 1) ? bk : bvp;
    float*       o    = (g == 0) ? q  : (g == 1) ? k  : v;
    float acc[8];
    const float b0 = bias[d];
    #pragma unroll
    for (int r = 0; r < 8; ++r) acc[r] = b0;
    #pragma unroll 4
    for (int c = 0; c < C_; ++c) {
        const float wv = W[c * D_ + d];
        #pragma unroll
        for (int r = 0; r < 8; ++r) acc[r] += xs[r][c] * wv;
    }
    #pragma unroll
    for (int r = 0; r < 8; ++r)
        o[(size_t)(row0 + r) * D_ + d] = acc[r];
}

// ---------------------------------------------------------------------------
// Pack mem_keys into bf16 hi/lo MFMA B-fragment layout (unchanged, for kNN).
// ---------------------------------------------------------------------------
__global__ __launch_bounds__(256) void kfrag_prep_kernel(
    const float* __restrict__ keys, unsigned short* __restrict__ khi,
    unsigned short* __restrict__ klo)
{
    const int tid = threadIdx.x;
    const int lane = tid & 63;
    const int ks = (tid >> 6) & 1;
    const int b  = blockIdx.x >> 9;
    const int nt = ((blockIdx.x & 511) << 1) | (tid >> 7);
    const int key = nt * 16 + (lane & 15);
    const float* src = keys + ((size_t)b * N_ + key) * D_ + ks * 32 + (lane >> 4) * 8;
    const size_t o = (((size_t)b * 1024 + nt) * 2 + ks) * 512 + (size_t)lane * 8;
    #pragma unroll
    for (int j = 0; j < 8; ++j) {
        const float xv = src[j];
        const unsigned short h = f2bf(xv);
        khi[o + j] = h;
        klo[o + j] = f2bf(xv - bf2f(h));
    }
}

// ---------------------------------------------------------------------------
// Pack causal K and V into bf16 MFMA fragment buffers.
// kcfrag[((b*128+n16)*2+ks)*512 + lane*8]: A-frag rows=keys (lane&15),
//   dims ks*32+(lane>>4)*8+j.
// vfrag[((b*32+n64)*8+ks*4+dt)*512 + lane*8]: A-frag of V^T: rows=dims
//   dt*16+(lane&15), contraction keys n64*64+ks*32+(lane>>4)*8+j.
// ---------------------------------------------------------------------------
__global__ __launch_bounds__(256) void causal_prep_kernel(
    const float* __restrict__ k, const float* __restrict__ v,
    unsigned short* __restrict__ kcfrag, unsigned short* __restrict__ vfrag)
{
    __shared__ float vtile[64][68];
    const int tid = threadIdx.x;
    const int b = blockIdx.x >> 5;
    const int n64 = blockIdx.x & 31;
    const int w = tid >> 6, lane = tid & 63;
    const int q16 = lane & 15, g = lane >> 4;

    // stage V rows n64*64..+63 into LDS (coalesced float4)
    const float4* in4 = (const float4*)(v + ((size_t)b * T_ + n64 * 64) * D_);
    #pragma unroll
    for (int p = 0; p < 4; ++p) {
        const int fi = tid + p * 256;
        const int row = fi >> 4, c4 = fi & 15;
        *(float4*)&vtile[row][c4 * 4] = in4[fi];
    }

    // kcfrag: wave w owns 16-key tile n16 = n64*4 + w (reads global k, no LDS dep)
    {
        const int key = (n64 * 4 + w) * 16 + q16;
        #pragma unroll
        for (int ks = 0; ks < 2; ++ks) {
            const float* src = k + ((size_t)b * T_ + key) * D_ + ks * 32 + g * 8;
            const float4 x0 = *(const float4*)(src);
            const float4 x1 = *(const float4*)(src + 4);
            unsigned short* dst = kcfrag
                + ((((size_t)b * 128 + n64 * 4 + w) * 2 + ks) * 512) + (size_t)lane * 8;
            dst[0] = f2bf(x0.x); dst[1] = f2bf(x0.y); dst[2] = f2bf(x0.z); dst[3] = f2bf(x0.w);
            dst[4] = f2bf(x1.x); dst[5] = f2bf(x1.y); dst[6] = f2bf(x1.z); dst[7] = f2bf(x1.w);
        }
    }
    __syncthreads();

    // vfrag: wave w = dim-tile dt
    #pragma unroll
    for (int ks = 0; ks < 2; ++ks) {
        unsigned short* dst = vfrag
            + ((((size_t)b * 32 + n64) * 8 + ks * 4 + w) * 512) + (size_t)lane * 8;
        #pragma unroll
        for (int j = 0; j < 8; ++j)
            dst[j] = f2bf(vtile[ks * 32 + g * 8 + j][w * 16 + q16]);
    }
}

// ---------------------------------------------------------------------------
// Causal flash attention (MFMA, bf16).  Block = (b, qt16): 16 queries.
// 4 waves split the key-tile range round-robin (intra-block split-K);
// online softmax per wave; partials merged via LDS; writes outc directly.
// S^T = K·Q^T (A=K-frag, B=Q-frag): C col=query (lane&15), row=key sub-row.
// O^T = V^T·P (A=V^T-frag, B=P-frag): C col=query, row=dim sub-row.
// ---------------------------------------------------------------------------
__global__ __launch_bounds__(256) void causal_flash_kernel(
    const float* __restrict__ qg,
    const unsigned short* __restrict__ kcfrag, const unsigned short* __restrict__ vfrag,
    float* __restrict__ outc)
{
    __shared__ unsigned int plds[64][36];   // P relayout, per-wave rows (stride 36 u32 = 16B-aligned)
    __shared__ float po[4][64][17];         // partial O^T per wave [dim][query]
    __shared__ float pml[4][2][16];         // partial m, l per wave
    const int tid = threadIdx.x;
    const int w = tid >> 6, lane = tid & 63;
    const int q16 = lane & 15, g = lane >> 4;
    const int b = blockIdx.x >> 7;
    const int qt = blockIdx.x & 127;
    const int t0 = qt * 16;
    const int qglob = t0 + q16;
    const int n64 = (qt >> 2) + 1;          // key tiles covering 0..t0+15

    // Q B-frag: col = q16, dims ks*32 + g*8 + j  (plain bf16)
    short8_t qf[2];
    #pragma unroll
    for (int ks = 0; ks < 2; ++ks) {
        const float* src = qg + ((size_t)b * T_ + qglob) * D_ + ks * 32 + g * 8;
        const float4 x0 = *(const float4*)(src);
        const float4 x1 = *(const float4*)(src + 4);
        qf[ks][0] = (short)f2bf(x0.x); qf[ks][1] = (short)f2bf(x0.y);
        qf[ks][2] = (short)f2bf(x0.z); qf[ks][3] = (short)f2bf(x0.w);
        qf[ks][4] = (short)f2bf(x1.x); qf[ks][5] = (short)f2bf(x1.y);
        qf[ks][6] = (short)f2bf(x1.z); qf[ks][7] = (short)f2bf(x1.w);
    }

    float m = -1.0e30f, l = 0.f;
    f32x4 o[4];
    #pragma unroll
    for (int dt = 0; dt < 4; ++dt) o[dt] = (f32x4){0.f, 0.f, 0.f, 0.f};

    const int qrow = w * 16 + q16;          // this wave's plds row

    for (int n = w; n < n64; n += 4) {
        // ---- S^T strip: 64 keys x 16 queries
        short8_t kf[4][2];
        #pragma unroll
        for (int a = 0; a < 4; ++a)
            #pragma unroll
            for (int ks = 0; ks < 2; ++ks)
                kf[a][ks] = *(const short8_t*)(kcfrag
                    + ((((size_t)b * 128 + n * 4 + a) * 2 + ks) * 512) + (size_t)lane * 8);
        f32x4 st[4];
        #pragma unroll
        for (int a = 0; a < 4; ++a) {
            st[a] = (f32x4){0.f, 0.f, 0.f, 0.f};
            st[a] = __builtin_amdgcn_mfma_f32_16x16x32_bf16(kf[a][0], qf[0], st[a], 0, 0, 0);
            st[a] = __builtin_amdgcn_mfma_f32_16x16x32_bf16(kf[a][1], qf[1], st[a], 0, 0, 0);
        }

        // ---- mask + scale + online softmax (query = q16; row spread over g)
        float sv[4][4];
        float pm = -1.0e30f;
        #pragma unroll
        for (int a = 0; a < 4; ++a)
            #pragma unroll
            for (int r = 0; r < 4; ++r) {
                const int kk = n * 64 + a * 16 + g * 4 + r;
                float x = st[a][r] * SCALE;
                x = (kk <= qglob) ? x : -1.0e31f;
                sv[a][r] = x;
                pm = fmaxf(pm, x);
            }
        pm = fmaxf(pm, __shfl_xor(pm, 16));
        pm = fmaxf(pm, __shfl_xor(pm, 32));
        const float mn = fmaxf(m, pm);
        const float al = __expf(m - mn);
        float rs = 0.f;
        float ev[4][4];
        #pragma unroll
        for (int a = 0; a < 4; ++a)
            #pragma unroll
            for (int r = 0; r < 4; ++r) {
                const float e = __expf(sv[a][r] - mn);
                ev[a][r] = e;
                rs += e;
            }
        rs += __shfl_xor(rs, 16);
        rs += __shfl_xor(rs, 32);
        l = l * al + rs;
        m = mn;
        #pragma unroll
        for (int dt = 0; dt < 4; ++dt) o[dt] *= al;

        // ---- P -> bf16 -> plds (B-frag relayout), then PV MFMA
        #pragma unroll
        for (int a = 0; a < 4; ++a)
            #pragma unroll
            for (int rp = 0; rp < 2; ++rp)
                plds[qrow][a * 8 + g * 2 + rp] =
                    (unsigned)f2bf(ev[a][2 * rp]) | ((unsigned)f2bf(ev[a][2 * rp + 1]) << 16);
        #pragma unroll
        for (int ks = 0; ks < 2; ++ks) {
            const short8_t pf = *(const short8_t*)&plds[qrow][ks * 16 + g * 4];
            #pragma unroll
            for (int dt = 0; dt < 4; ++dt) {
                const short8_t vf = *(const short8_t*)(vfrag
                    + ((((size_t)b * 32 + n) * 8 + ks * 4 + dt) * 512) + (size_t)lane * 8);
                o[dt] = __builtin_amdgcn_mfma_f32_16x16x32_bf16(vf, pf, o[dt], 0, 0, 0);
            }
        }
    }

    // ---- write partials, merge, output
    #pragma unroll
    for (int dt = 0; dt < 4; ++dt)
        #pragma unroll
        for (int r = 0; r < 4; ++r)
            po[w][dt * 16 + g * 4 + r][q16] = o[dt][r];
    if (g == 0) { pml[w][0][q16] = m; pml[w][1][q16] = l; }
    __syncthreads();

    {
        const int q = tid & 15;
        const int dgrp = tid >> 4;          // 0..15
        float mw[4], lw[4];
        #pragma unroll
        for (int ww = 0; ww < 4; ++ww) { mw[ww] = pml[ww][0][q]; lw[ww] = pml[ww][1][q]; }
        const float M = fmaxf(fmaxf(mw[0], mw[1]), fmaxf(mw[2], mw[3]));
        float wgt[4], L = 0.f;
        #pragma unroll
        for (int ww = 0; ww < 4; ++ww) {
            wgt[ww] = __expf(mw[ww] - M);
            L += lw[ww] * wgt[ww];
        }
        const float inv = 1.0f / L;
        float4 res;
        float* rp = &res.x;
        #pragma unroll
        for (int i = 0; i < 4; ++i) {
            const int d = dgrp * 4 + i;
            float s = 0.f;
            #pragma unroll
            for (int ww = 0; ww < 4; ++ww) s += po[ww][d][q] * wgt[ww];
            rp[i] = s * inv;
        }
        *(float4*)(outc + ((size_t)b * T_ + t0 + q) * D_ + dgrp * 4) = res;
    }
}

// ---------------------------------------------------------------------------
// kNN v6 (unchanged from round 6): MFMA scoring with bf16 hi/lo split.
// ---------------------------------------------------------------------------
__global__ __launch_bounds__(256) void knn_mfma_kernel(
    const float* __restrict__ qg,
    const unsigned short* __restrict__ khi, const unsigned short* __restrict__ klo,
    const float* __restrict__ mem_vals, const float* __restrict__ outc,
    const float* __restrict__ gate, float* __restrict__ outp)
{
    __shared__ float sc_lds[16][256];
    const int tid = threadIdx.x;
    const int w = tid >> 6, lane = tid & 63;
    const int bid = blockIdx.x;
    const int b  = (bid & 7) >> 1;
    const int qt = ((bid >> 3) << 1) | (bid & 1);
    const int t0 = qt * 16;

    short8_t qh[2], ql[2];
    {
        const int qrow = t0 + (lane & 15);
        const float* qs = qg + ((size_t)b * T_ + qrow) * D_ + (lane >> 4) * 8;
        #pragma unroll
        for (int ks2 = 0; ks2 < 2; ++ks2) {
            #pragma unroll
            for (int j = 0; j < 8; ++j) {
                const float xv = qs[ks2 * 32 + j];
                const unsigned short h = f2bf(xv);
                qh[ks2][j] = (short)h;
                ql[ks2][j] = (short)f2bf(xv - bf2f(h));
            }
        }
    }

    float rv[4];  int rid_[4];  float t32[4];
    #pragma unroll
    for (int qq = 0; qq < 4; ++qq) {
        rv[qq] = NEGINF; rid_[qq] = 0x7fffffff; t32[qq] = NEGINF;
    }

    for (int c = 0; c < 64; ++c) {
        if (c) __syncthreads();

        #pragma unroll
        for (int tt = 0; tt < 4; ++tt) {
            const int tl = w + 4 * tt;
            const size_t kb = (((size_t)b * 1024 + (size_t)c * 16 + tl) * 2) * 512
                            + (size_t)lane * 8;
            const short8_t kh0 = *(const short8_t*)(khi + kb);
            const short8_t kh1 = *(const short8_t*)(khi + kb + 512);
            const short8_t kl0 = *(const short8_t*)(klo + kb);
            const short8_t kl1 = *(const short8_t*)(klo + kb + 512);
            f32x4 acc = {0.f, 0.f, 0.f, 0.f};
            acc = __builtin_amdgcn_mfma_f32_16x16x32_bf16(qh[0], kh0, acc, 0, 0, 0);
            acc = __builtin_amdgcn_mfma_f32_16x16x32_bf16(qh[1], kh1, acc, 0, 0, 0);
            acc = __builtin_amdgcn_mfma_f32_16x16x32_bf16(qh[0], kl0, acc, 0, 0, 0);
            acc = __builtin_amdgcn_mfma_f32_16x16x32_bf16(qh[1], kl1, acc, 0, 0, 0);
            acc = __builtin_amdgcn_mfma_f32_16x16x32_bf16(ql[0], kh0, acc, 0, 0, 0);
            acc = __builtin_amdgcn_mfma_f32_16x16x32_bf16(ql[1], kh1, acc, 0, 0, 0);
            const int qrow4 = (lane >> 4) * 4;
            const int col = tl * 16 + (lane & 15);
            #pragma unroll
            for (int r = 0; r < 4; ++r) sc_lds[qrow4 + r][col] = acc[r];
        }
        __syncthreads();

        float s4[4][4];
        #pragma unroll
        for (int qq = 0; qq < 4; ++qq)
            *(float4*)(&s4[qq][0]) = *(const float4*)&sc_lds[w * 4 + qq][lane * 4];

        if (c == 0) {
            #pragma unroll
            for (int qq = 0; qq < 4; ++qq) {
                float lmax = NEGINF; int lslot = 0;
                #pragma unroll
                for (int j = 0; j < 4; ++j)
                    if (s4[qq][j] > lmax) { lmax = s4[qq][j]; lslot = j; }
                for (int it = 0; it < 32; ++it) {
                    float wm = lmax;
                    #pragma unroll
                    for (int off = 32; off; off >>= 1)
                        wm = fmaxf(wm, __shfl_xor(wm, off));
                    const unsigned long long bal = __ballot(lmax == wm);
                    const int winner = __ffsll((unsigned long long)bal) - 1;
                    const int wslot  = __shfl(lslot, winner);
                    const int widx   = (winner << 2) + (wslot & 3);
                    const unsigned long long gb = __ballot((lane < K_) && (rv[qq] > wm));
                    const int pos = __popcll(gb);
                    const float sv = __shfl_up(rv[qq], 1);
                    const int   si = __shfl_up(rid_[qq], 1);
                    if (lane > pos)       { rv[qq] = sv; rid_[qq] = si; }
                    else if (lane == pos) { rv[qq] = wm; rid_[qq] = widx; }
                    if (lane == winner) {
                        float nm = NEGINF; int ns = 0;
                        #pragma unroll
                        for (int j = 0; j < 4; ++j) {
                            const float vj = (j == lslot) ? NEGINF : s4[qq][j];
                            s4[qq][j] = vj;
                            if (vj > nm) { nm = vj; ns = j; }
                        }
                        lmax = nm; lslot = ns;
                    }
                }
                t32[qq] = __shfl(rv[qq], 31);
            }
        } else {
            #pragma unroll
            for (int qq = 0; qq < 4; ++qq) {
                unsigned int mask = 0u;
                #pragma unroll
                for (int j = 0; j < 4; ++j)
                    mask |= (s4[qq][j] > t32[qq]) ? (1u << j) : 0u;
                while (true) {
                    const unsigned long long bb = __ballot(mask != 0u);
                    if (!bb) break;
                    const int L  = __ffsll(bb) - 1;
                    const unsigned int mL = (unsigned int)__shfl((int)mask, L);
                    const int j  = __ffs(mL) - 1;
                    float xl = s4[qq][0];
                    #pragma unroll
                    for (int jj = 1; jj < 4; ++jj)
                        xl = (j == jj) ? s4[qq][jj] : xl;
                    const float xv = __shfl(xl, L);
                    const int   xi = (c << 8) + (L << 2) + j;
                    if (lane == L) mask &= ~(1u << j);
                    if (xv > t32[qq]) {
                        const unsigned long long gb =
                            __ballot((lane < K_) && (rv[qq] > xv));
                        const int pos = __popcll(gb);
                        const float sv = __shfl_up(rv[qq], 1);
                        const int   si = __shfl_up(rid_[qq], 1);
                        if (lane > pos)       { rv[qq] = sv; rid_[qq] = si; }
                        else if (lane == pos) { rv[qq] = xv; rid_[qq] = xi; }
                        t32[qq] = __shfl(rv[qq], 31);
                    }
                }
            }
        }
    }

    const float gv = gate[0];
    const float* vb = mem_vals + (size_t)b * N_ * D_;
    #pragma unroll
    for (int qq = 0; qq < 4; ++qq) {
        const float m = __shfl(rv[qq], 0);
        float wgt = (lane < K_) ? __expf((rv[qq] - m) * SCALE) : 0.f;
        float ssum = wgt;
        #pragma unroll
        for (int off = 32; off; off >>= 1) ssum += __shfl_xor(ssum, off);
        float acc = 0.f;
        for (int i = 0; i < K_; ++i) {
            const float wi = __shfl(wgt, i);
            const int   ii = __shfl(rid_[qq], i);
            acc += wi * vb[(size_t)ii * D_ + lane];
        }
        const size_t o = ((size_t)(b * T_ + t0 + w * 4 + qq)) * D_ + lane;
        outp[o] = outc[o] * gv + (acc / ssum) * (1.f - gv);
    }
}

extern "C" void kernel_launch(void* const* d_in, const int* in_sizes, int n_in,
                              void* d_out, int out_size, void* d_ws, size_t ws_size,
                              hipStream_t stream) {
    const float* x        = (const float*)d_in[0];
    const float* mem_keys = (const float*)d_in[1];
    const float* mem_vals = (const float*)d_in[2];
    const float* Wq       = (const float*)d_in[3];
    const float* bq       = (const float*)d_in[4];
    const float* Wk       = (const float*)d_in[5];
    const float* bk       = (const float*)d_in[6];
    const float* Wv       = (const float*)d_in[7];
    const float* bv       = (const float*)d_in[8];
    const float* gate     = (const float*)d_in[9];
    float* out = (float*)d_out;

    const size_t btd = (size_t)B_ * T_ * D_;   // 524288
    float* q    = (float*)d_ws;
    float* k    = q + btd;
    float* v    = k + btd;
    float* outc = v + btd;
    unsigned short* khi    = (unsigned short*)(outc + btd);   // 8 MB
    unsigned short* klo    = khi + (size_t)B_ * N_ * D_;      // 8 MB
    unsigned short* kcfrag = klo + (size_t)B_ * N_ * D_;      // 1 MB
    unsigned short* vfrag  = kcfrag + btd;                    // 1 MB

    qkv_proj_kernel<<<B_ * T_ / 8, 192, 0, stream>>>(x, Wq, bq, Wk, bk, Wv, bv, q, k, v);
    kfrag_prep_kernel<<<B_ * 512, 256, 0, stream>>>(mem_keys, khi, klo);
    causal_prep_kernel<<<B_ * 32, 256, 0, stream>>>(k, v, kcfrag, vfrag);
    causal_flash_kernel<<<B_ * 128, 256, 0, stream>>>(q, kcfrag, vfrag, outc);
    knn_mfma_kernel<<<(B_ * T_) / 16, 256, 0, stream>>>(q, khi, klo, mem_vals, outc, gate, out);
}